// Round 11
// baseline (21.729 us; speedup 1.0000x reference)
//
#include <hip/hip_runtime.h>
#include <math.h>

namespace {

constexpr int   kB      = 8192;
constexpr int   kD      = 256;      // dims; 64 lanes * float4
constexpr float kMargin = 1.0f;
constexpr float kEps    = 1e-12f;

typedef float f32x4 __attribute__((ext_vector_type(4)));

// Normal (cacheable) row-gather -- used for the ent tables (200 MB combined,
// fits the 256 MB Infinity Cache; warm across graph replays).
__device__ inline float4 ld4(const float* __restrict__ tab, int row, int lane) {
    return reinterpret_cast<const float4*>(tab + (size_t)row * kD)[lane];
}

// Non-temporal row-gather -- used for the rel tables: stream them from DRAM
// and keep them OUT of the LLC so the ent tables stay resident.
__device__ inline float4 ld4nt(const float* __restrict__ tab, int row, int lane) {
    const f32x4* p = reinterpret_cast<const f32x4*>(tab + (size_t)row * kD) + lane;
    f32x4 v = __builtin_nontemporal_load(p);
    return make_float4(v.x, v.y, v.z, v.w);
}

__device__ inline float dot4(const float4& a, const float4& b) {
    return a.x * b.x + a.y * b.y + a.z * b.z + a.w * b.w;
}

// a + b * s
__device__ inline float4 fma4(const float4& a, const float4& b, float s) {
    float4 r;
    r.x = fmaf(b.x, s, a.x);
    r.y = fmaf(b.y, s, a.y);
    r.z = fmaf(b.z, s, a.z);
    r.w = fmaf(b.w, s, a.w);
    return r;
}

// One wave per (row, phase): pos and neg triples of a row run concurrently
// in sibling waves of the same block; scalar losses meet in LDS.
__global__ __launch_bounds__(256, 8) void transd_kernel(
    const int* __restrict__ X, const int* __restrict__ Y,
    const float* __restrict__ ent_emb, const float* __restrict__ rel_emb,
    const float* __restrict__ ent_proj, const float* __restrict__ rel_proj,
    float* __restrict__ out)
{
    __shared__ float ls[2][2];   // [row_in_block][phase]

    const int tid  = threadIdx.x;
    const int wid  = tid >> 6;         // 0..3
    const int lane = tid & 63;
    const int rin  = wid >> 1;         // row within block: 0,1
    const int ph   = wid & 1;          // 0 = pos(X), 1 = neg(Y)
    const int b    = blockIdx.x * 2 + rin;

    const int* __restrict__ T = ph ? Y : X;
    const int ih = T[b * 3 + 0], ir = T[b * 3 + 1], it = T[b * 3 + 2];

    // 6 coalesced 1KB row-gathers, all issued before any use.
    // ent tables: cacheable (LLC-resident); rel tables: non-temporal stream.
    float4 h  = ld4  (ent_emb,  ih, lane);
    float4 r  = ld4nt(rel_emb,  ir, lane);
    float4 t  = ld4  (ent_emb,  it, lane);
    float4 hp = ld4  (ent_proj, ih, lane);
    float4 rp = ld4nt(rel_proj, ir, lane);
    float4 tp = ld4  (ent_proj, it, lane);

    // projection dots: dot(h_p, h), dot(t_p, t)
    float dh = dot4(hp, h);
    float dt = dot4(tp, t);
    #pragma unroll
    for (int off = 1; off < 64; off <<= 1) {
        dh += __shfl_xor(dh, off, 64);
        dt += __shfl_xor(dt, off, 64);
    }

    // h_ = h + r_p * dh; t_ = t + r_p * dt
    float4 h_ = fma4(h, rp, dh);
    float4 t_ = fma4(t, rp, dt);

    // squared norms of h_, r, t_
    float qh = dot4(h_, h_);
    float qr = dot4(r, r);
    float qt = dot4(t_, t_);
    #pragma unroll
    for (int off = 1; off < 64; off <<= 1) {
        qh += __shfl_xor(qh, off, 64);
        qr += __shfl_xor(qr, off, 64);
        qt += __shfl_xor(qt, off, 64);
    }

    const float inh = 1.0f / fmaxf(sqrtf(qh), kEps);
    const float inr = 1.0f / fmaxf(sqrtf(qr), kEps);
    const float int_ = 1.0f / fmaxf(sqrtf(qt), kEps);

    // s = normalize(h_) + normalize(r) - normalize(t_)
    float4 sv;
    sv.x = h_.x * inh + r.x * inr - t_.x * int_;
    sv.y = h_.y * inh + r.y * inr - t_.y * int_;
    sv.z = h_.z * inh + r.z * inr - t_.z * int_;
    sv.w = h_.w * inh + r.w * inr - t_.w * int_;

    float ss = dot4(sv, sv);
    #pragma unroll
    for (int off = 1; off < 64; off <<= 1) {
        ss += __shfl_xor(ss, off, 64);
    }

    if (lane == 0) ls[rin][ph] = sqrtf(ss);
    __syncthreads();

    if (ph == 0 && lane == 0) {
        out[b] = fmaxf(ls[rin][0] - ls[rin][1] + kMargin, 0.0f);
    }
}

} // namespace

extern "C" void kernel_launch(void* const* d_in, const int* in_sizes, int n_in,
                              void* d_out, int out_size, void* d_ws, size_t ws_size,
                              hipStream_t stream) {
    const int*   X        = (const int*)  d_in[0];
    const int*   Y        = (const int*)  d_in[1];
    const float* ent_emb  = (const float*)d_in[2];
    const float* rel_emb  = (const float*)d_in[3];
    const float* ent_proj = (const float*)d_in[4];
    const float* rel_proj = (const float*)d_in[5];
    float*       out      = (float*)d_out;

    // 2 rows per 256-thread block: waves (pos,neg) x 2 rows
    const int threads = 256;
    const int blocks  = kB / 2;   // 4096
    transd_kernel<<<blocks, threads, 0, stream>>>(
        X, Y, ent_emb, rel_emb, ent_proj, rel_proj, out);
}

// Round 12
// 20.305 us; speedup vs baseline: 1.0702x; 1.0702x over previous
//
#include <hip/hip_runtime.h>
#include <math.h>

namespace {

constexpr int   kB      = 8192;
constexpr int   kD      = 256;      // dims; 64 lanes * float4
constexpr float kMargin = 1.0f;
constexpr float kEps    = 1e-12f;

typedef float f32x4 __attribute__((ext_vector_type(4)));

// Non-temporal row-gather: the tables (410 MB, random access, ~8% reuse)
// thrash L1/L2 -- mark ALL table loads streaming / early-evict. Measured
// -4.5% vs cacheable (R9 vs R6); selective nt (rel-only) was WORSE (R11),
// so the win is cache-pollution avoidance, not LLC partitioning.
__device__ inline float4 ld4nt(const float* __restrict__ tab, int row, int lane) {
    const f32x4* p = reinterpret_cast<const f32x4*>(tab + (size_t)row * kD) + lane;
    f32x4 v = __builtin_nontemporal_load(p);
    return make_float4(v.x, v.y, v.z, v.w);
}

__device__ inline float dot4(const float4& a, const float4& b) {
    return a.x * b.x + a.y * b.y + a.z * b.z + a.w * b.w;
}

// a + b * s
__device__ inline float4 fma4(const float4& a, const float4& b, float s) {
    float4 r;
    r.x = fmaf(b.x, s, a.x);
    r.y = fmaf(b.y, s, a.y);
    r.z = fmaf(b.z, s, a.z);
    r.w = fmaf(b.w, s, a.w);
    return r;
}

// One wave per (row, phase): pos and neg triples of a row run concurrently
// in sibling waves of the same block; scalar losses meet in LDS.
__global__ __launch_bounds__(256, 8) void transd_kernel(
    const int* __restrict__ X, const int* __restrict__ Y,
    const float* __restrict__ ent_emb, const float* __restrict__ rel_emb,
    const float* __restrict__ ent_proj, const float* __restrict__ rel_proj,
    float* __restrict__ out)
{
    __shared__ float ls[2][2];   // [row_in_block][phase]

    const int tid  = threadIdx.x;
    const int wid  = tid >> 6;         // 0..3
    const int lane = tid & 63;
    const int rin  = wid >> 1;         // row within block: 0,1
    const int ph   = wid & 1;          // 0 = pos(X), 1 = neg(Y)
    const int b    = blockIdx.x * 2 + rin;

    const int* __restrict__ T = ph ? Y : X;
    const int ih = T[b * 3 + 0], ir = T[b * 3 + 1], it = T[b * 3 + 2];

    // 6 coalesced 1KB row-gathers, all issued before any use.
    float4 h  = ld4nt(ent_emb,  ih, lane);
    float4 r  = ld4nt(rel_emb,  ir, lane);
    float4 t  = ld4nt(ent_emb,  it, lane);
    float4 hp = ld4nt(ent_proj, ih, lane);
    float4 rp = ld4nt(rel_proj, ir, lane);
    float4 tp = ld4nt(ent_proj, it, lane);

    // projection dots: dot(h_p, h), dot(t_p, t)
    float dh = dot4(hp, h);
    float dt = dot4(tp, t);
    #pragma unroll
    for (int off = 1; off < 64; off <<= 1) {
        dh += __shfl_xor(dh, off, 64);
        dt += __shfl_xor(dt, off, 64);
    }

    // h_ = h + r_p * dh; t_ = t + r_p * dt
    float4 h_ = fma4(h, rp, dh);
    float4 t_ = fma4(t, rp, dt);

    // squared norms of h_, r, t_
    float qh = dot4(h_, h_);
    float qr = dot4(r, r);
    float qt = dot4(t_, t_);
    #pragma unroll
    for (int off = 1; off < 64; off <<= 1) {
        qh += __shfl_xor(qh, off, 64);
        qr += __shfl_xor(qr, off, 64);
        qt += __shfl_xor(qt, off, 64);
    }

    const float inh = 1.0f / fmaxf(sqrtf(qh), kEps);
    const float inr = 1.0f / fmaxf(sqrtf(qr), kEps);
    const float int_ = 1.0f / fmaxf(sqrtf(qt), kEps);

    // s = normalize(h_) + normalize(r) - normalize(t_)
    float4 sv;
    sv.x = h_.x * inh + r.x * inr - t_.x * int_;
    sv.y = h_.y * inh + r.y * inr - t_.y * int_;
    sv.z = h_.z * inh + r.z * inr - t_.z * int_;
    sv.w = h_.w * inh + r.w * inr - t_.w * int_;

    float ss = dot4(sv, sv);
    #pragma unroll
    for (int off = 1; off < 64; off <<= 1) {
        ss += __shfl_xor(ss, off, 64);
    }

    if (lane == 0) ls[rin][ph] = sqrtf(ss);
    __syncthreads();

    if (ph == 0 && lane == 0) {
        out[b] = fmaxf(ls[rin][0] - ls[rin][1] + kMargin, 0.0f);
    }
}

} // namespace

extern "C" void kernel_launch(void* const* d_in, const int* in_sizes, int n_in,
                              void* d_out, int out_size, void* d_ws, size_t ws_size,
                              hipStream_t stream) {
    const int*   X        = (const int*)  d_in[0];
    const int*   Y        = (const int*)  d_in[1];
    const float* ent_emb  = (const float*)d_in[2];
    const float* rel_emb  = (const float*)d_in[3];
    const float* ent_proj = (const float*)d_in[4];
    const float* rel_proj = (const float*)d_in[5];
    float*       out      = (float*)d_out;

    // 2 rows per 256-thread block: waves (pos,neg) x 2 rows
    const int threads = 256;
    const int blocks  = kB / 2;   // 4096
    transd_kernel<<<blocks, threads, 0, stream>>>(
        X, Y, ent_emb, rel_emb, ent_proj, rel_proj, out);
}